// Round 13
// baseline (269.949 us; speedup 1.0000x reference)
//
#include <hip/hip_runtime.h>
#include <hip/hip_bf16.h>

// SlotAttention: B=128, N=8192, S=4, D=32, ITERS=3.  Output dtype: float32.
//
// 4 launches: pass<0> (init prologue) -> pass<1> -> pass<2> (update prologues)
// -> final.  Each pass block: redundant per-block chain (init or GRU/MLP
// update -> qt) then stream its 256-row chunk with DPP quad-perm reductions
// and prefetch depth 2.  Cn=32 chunks/batch (4096 blocks) for load balance.
// Algebra: logit_s = rs*(qg_s.x - mean*qgs_s) + qe_s ;
//          u = gamma o (Sum al*x - Sum al*mean) + (Sum w) beta, al = w*rs.

#define Bn 128
#define Nn 8192
#define Sn 4
#define Dn 32
#define SCALE 0.17677669529663687f  // D^-0.5
#define RENORM (1.0f / (1.0f + (float)Nn * 1e-8f))

#define Cn 32                 // chunks per batch -> 4096 pass blocks
#define RPB (Nn / Cn)         // 256 rows per pass-block
#define PT 256                // pass threads (4 waves)
#define RSTEP (PT / 4)        // 64 rows per step (4 lanes per row)
#define NSTEP (RPB / RSTEP)   // 4 steps

#define WS_REQ ((size_t)(3 * Bn * Sn * Dn + 3 * Bn * Cn * Sn * Dn + 6 * Bn * Cn * Sn) * 4)

__device__ __forceinline__ float sigmoidf_(float v) { return 1.0f / (1.0f + __expf(-v)); }

// DPP cross-lane add within each quad (VALU pipe, no LDS latency).
// quad_perm [1,0,3,2] = 0xB1 (xor 1);  [2,3,0,1] = 0x4E (xor 2).
template<int CTRL>
__device__ __forceinline__ float dpp_xadd(float v) {
    int p = __builtin_amdgcn_update_dpp(0, __float_as_int(v), CTRL, 0xF, 0xF, true);
    return v + __int_as_float(p);
}
#define DPP_X1 0xB1
#define DPP_X2 0x4E

// ---------------------------------------------------------------------------
// chain: compute slots_i (KIND=0: init; KIND=1: GRU/MLP update from partials)
// and optionally qt_i into qt_sh. Uniform syncs; threads >=128 idle through.
// ---------------------------------------------------------------------------
template<int KIND, int WANT_QT>
__device__ __forceinline__ void chain_fn(
    int b, int tid,
    const float* __restrict__ pa_prev, const float* __restrict__ pb_prev,
    const float* __restrict__ ps_prev,
    const float* __restrict__ slots_prev,
    const float* __restrict__ noise, const float* __restrict__ mu,
    const float* __restrict__ logsig,
    const float* __restrict__ lnx_g, const float* __restrict__ lnx_b,
    const float* __restrict__ Wv,
    const float* __restrict__ Wih, const float* __restrict__ Whh,
    const float* __restrict__ bih, const float* __restrict__ bhh,
    const float* __restrict__ W1, const float* __restrict__ b1v,
    const float* __restrict__ W2, const float* __restrict__ b2v,
    const float* __restrict__ lns_g, const float* __restrict__ lns_b,
    const float* __restrict__ lnff_g, const float* __restrict__ lnff_b,
    const float* __restrict__ Wq, const float* __restrict__ Wk,
    float (*qt_sh)[Dn], float (*ta)[Dn], float (*tb)[Dn],
    float* __restrict__ store)
{
    const int s = (tid >> 5) & 3, d = tid & 31;
    const bool act = tid < 128;
    float sfin = 0.f;

    if constexpr (KIND == 0) {
        if (act)
            sfin = mu[d] + noise[(b * Sn + s) * Dn + d] * __expf(logsig[d]);
    } else {
        float sv_c = 0.f, lnffv = 0.f;
        if (act) {
            float PA = 0.f, PB = 0.f, PS = 0.f;
            #pragma unroll
            for (int c = 0; c < Cn; ++c) {
                PA += pa_prev[(((size_t)b * Cn + c) * Sn + s) * Dn + d];
                PB += pb_prev[((size_t)b * Cn + c) * Sn + s];
                PS += ps_prev[((size_t)b * Cn + c) * Sn + s];
            }
            float u = fmaf(lnx_g[d], PA - PB, PS * lnx_b[d]);
            ta[s][d] = (u / PS) * RENORM;                 // ubar
            tb[s][d] = slots_prev[(b * Sn + s) * Dn + d]; // sold
        }
        __syncthreads();
        float updv = 0.f;
        if (act) {
            #pragma unroll 8
            for (int j = 0; j < 32; ++j) updv = fmaf(Wv[d * 32 + j], ta[s][j], updv);
        }
        __syncthreads();
        if (act) ta[s][d] = updv;                        // upd
        __syncthreads();
        if (act) {
            float gi[3], gh[3];
            #pragma unroll
            for (int g3 = 0; g3 < 3; ++g3) {
                const int row = g3 * 32 + d;
                float a1 = bih[row], a2 = bhh[row];
                #pragma unroll 8
                for (int j = 0; j < 32; ++j) {
                    a1 = fmaf(Wih[row * 32 + j], ta[s][j], a1);
                    a2 = fmaf(Whh[row * 32 + j], tb[s][j], a2);
                }
                gi[g3] = a1; gh[g3] = a2;
            }
            float r  = sigmoidf_(gi[0] + gh[0]);
            float z  = sigmoidf_(gi[1] + gh[1]);
            float nn = tanhf(gi[2] + r * gh[2]);
            sv_c = (1.0f - z) * nn + z * tb[s][d];
            float sx = sv_c, sxx = sv_c * sv_c;
            #pragma unroll
            for (int m = 1; m <= 16; m <<= 1) { sx += __shfl_xor(sx, m); sxx += __shfl_xor(sxx, m); }
            float mean = sx * (1.0f / 32.0f);
            float var  = sxx * (1.0f / 32.0f) - mean * mean;
            lnffv = (sv_c - mean) * rsqrtf(var + 1e-5f) * lnff_g[d] + lnff_b[d];
        }
        __syncthreads();
        if (act) ta[s][d] = lnffv;
        __syncthreads();
        if (act) {
            float h = b1v[d];
            #pragma unroll 8
            for (int j = 0; j < 32; ++j) h = fmaf(W1[d * 32 + j], ta[s][j], h);
            tb[s][d] = fmaxf(h, 0.f);
        }
        __syncthreads();
        if (act) {
            float o = b2v[d];
            #pragma unroll 8
            for (int j = 0; j < 32; ++j) o = fmaf(W2[d * 32 + j], tb[s][j], o);
            sfin = sv_c + o;
        }
    }

    if (act && store) store[(b * Sn + s) * Dn + d] = sfin;

    if constexpr (WANT_QT) {
        float lnsv = 0.f;
        if (act) {
            float sx = sfin, sxx = sfin * sfin;
            #pragma unroll
            for (int m = 1; m <= 16; m <<= 1) { sx += __shfl_xor(sx, m); sxx += __shfl_xor(sxx, m); }
            float mean = sx * (1.0f / 32.0f);
            float var  = sxx * (1.0f / 32.0f) - mean * mean;
            lnsv = (sfin - mean) * rsqrtf(var + 1e-5f) * lns_g[d] + lns_b[d];
        }
        __syncthreads();
        if (act) ta[s][d] = lnsv;
        __syncthreads();
        if (act) {
            float q = 0.f;
            #pragma unroll 8
            for (int j = 0; j < 32; ++j) q = fmaf(Wq[d * 32 + j], ta[s][j], q);
            tb[s][d] = q;
        }
        __syncthreads();
        if (act) {
            float qv = 0.f;
            #pragma unroll 8
            for (int i = 0; i < 32; ++i) qv = fmaf(tb[s][i], Wk[i * 32 + d], qv);
            qt_sh[s][d] = qv * SCALE;
        }
        __syncthreads();
    }
}

// ---------------------------------------------------------------------------
// pass kernel: prologue chain; then stream 256 rows (DPP + prefetch-2).
// ---------------------------------------------------------------------------
template<int IT>
__global__ __launch_bounds__(PT)
void pass_k(const float* __restrict__ x,
            const float* __restrict__ noise, const float* __restrict__ mu,
            const float* __restrict__ logsig,
            const float* __restrict__ Wq, const float* __restrict__ Wk,
            const float* __restrict__ Wv,
            const float* __restrict__ Wih, const float* __restrict__ Whh,
            const float* __restrict__ bih, const float* __restrict__ bhh,
            const float* __restrict__ W1, const float* __restrict__ b1v,
            const float* __restrict__ W2, const float* __restrict__ b2v,
            const float* __restrict__ lnx_g, const float* __restrict__ lnx_b,
            const float* __restrict__ lns_g, const float* __restrict__ lns_b,
            const float* __restrict__ lnff_g, const float* __restrict__ lnff_b,
            const float* __restrict__ slots_prev, float* __restrict__ slots_cur,
            const float* __restrict__ pa_prev, const float* __restrict__ pb_prev,
            const float* __restrict__ ps_prev,
            float* __restrict__ pa_cur, float* __restrict__ pb_cur,
            float* __restrict__ ps_cur)
{
    const int c = blockIdx.x, b = blockIdx.y, tid = threadIdx.x;
    __shared__ float qt_sh[Sn][Dn], ta[Sn][Dn], tb[Sn][Dn];
    __shared__ float ls_pa[4][Sn][Dn];
    __shared__ float ls_pb[4][Sn];
    __shared__ float ls_ps[4][Sn];

    chain_fn<(IT == 0 ? 0 : 1), 1>(b, tid, pa_prev, pb_prev, ps_prev, slots_prev,
        noise, mu, logsig, lnx_g, lnx_b, Wv, Wih, Whh, bih, bhh, W1, b1v, W2, b2v,
        lns_g, lns_b, lnff_g, lnff_b, Wq, Wk,
        qt_sh, ta, tb, (c == 0) ? slots_cur : nullptr);

    const int sub = tid & 3, col0 = sub * 8, rg = tid >> 2;  // rg 0..63

    // prologue: qg = qt*gamma ; qgs = sum(qg) ; qe = qt.beta  (DPP sums)
    float qg[4][8], qgs[4], qe[4];
    {
        float g8[8], e8[8];
        #pragma unroll
        for (int k = 0; k < 8; ++k) { g8[k] = lnx_g[col0 + k]; e8[k] = lnx_b[col0 + k]; }
        #pragma unroll
        for (int s = 0; s < 4; ++s) {
            float sg = 0.f, se = 0.f;
            #pragma unroll
            for (int k = 0; k < 8; ++k) {
                float q = qt_sh[s][col0 + k];
                qg[s][k] = q * g8[k];
                sg += qg[s][k];
                se = fmaf(q, e8[k], se);
            }
            sg = dpp_xadd<DPP_X1>(sg); sg = dpp_xadd<DPP_X2>(sg);
            se = dpp_xadd<DPP_X1>(se); se = dpp_xadd<DPP_X2>(se);
            qgs[s] = sg; qe[s] = se;
        }
    }

    float pa[4][8], pb[4] = {0.f,0.f,0.f,0.f}, ps[4] = {0.f,0.f,0.f,0.f};
    #pragma unroll
    for (int s = 0; s < 4; ++s)
        #pragma unroll
        for (int k = 0; k < 8; ++k) pa[s][k] = 0.f;

    const float* xb = x + ((size_t)b * Nn + (size_t)c * RPB) * Dn;
    const float* base = xb + (size_t)rg * Dn + col0;

    // prefetch depth 2
    float4 v0  = *(const float4*)(base);
    float4 v1  = *(const float4*)(base + 4);
    float4 n10 = *(const float4*)(base + (size_t)RSTEP * Dn);
    float4 n11 = *(const float4*)(base + (size_t)RSTEP * Dn + 4);

    for (int t = 0; t < NSTEP; ++t) {
        const int t2 = (t + 2 < NSTEP) ? t + 2 : NSTEP - 1;   // clamped re-read
        const float* p2 = base + (size_t)(t2 * RSTEP) * Dn;
        float4 n20 = *(const float4*)(p2);
        float4 n21 = *(const float4*)(p2 + 4);

        float xv[8] = {v0.x, v0.y, v0.z, v0.w, v1.x, v1.y, v1.z, v1.w};

        float sx = 0.f, sxx = 0.f, ds[4] = {0.f,0.f,0.f,0.f};
        #pragma unroll
        for (int k = 0; k < 8; ++k) {
            sx += xv[k];
            sxx = fmaf(xv[k], xv[k], sxx);
            #pragma unroll
            for (int s = 0; s < 4; ++s) ds[s] = fmaf(xv[k], qg[s][k], ds[s]);
        }
        sx  = dpp_xadd<DPP_X1>(sx);   sx  = dpp_xadd<DPP_X2>(sx);
        sxx = dpp_xadd<DPP_X1>(sxx);  sxx = dpp_xadd<DPP_X2>(sxx);
        #pragma unroll
        for (int s = 0; s < 4; ++s) {
            ds[s] = dpp_xadd<DPP_X1>(ds[s]);
            ds[s] = dpp_xadd<DPP_X2>(ds[s]);
        }

        float mean = sx * (1.0f / 32.0f);
        float var  = sxx * (1.0f / 32.0f) - mean * mean;
        float rs   = rsqrtf(var + 1e-5f);

        #pragma unroll
        for (int s = 0; s < 4; ++s) {
            float tt = fmaf(-mean, qgs[s], ds[s]);
            float lg = fmaf(rs, tt, qe[s]);
            float w  = __expf(lg);                  // |logit| <~ 8 -> safe
            float al = w * rs;
            ps[s] += w;
            pb[s] = fmaf(al, mean, pb[s]);
            #pragma unroll
            for (int k = 0; k < 8; ++k) pa[s][k] = fmaf(al, xv[k], pa[s][k]);
        }
        v0 = n10; v1 = n11; n10 = n20; n11 = n21;
    }

    // reduce across the 16 row-groups of each wave (once per block)
    #pragma unroll
    for (int m = 4; m <= 32; m <<= 1) {
        #pragma unroll
        for (int s = 0; s < 4; ++s) {
            ps[s] += __shfl_xor(ps[s], m);
            pb[s] += __shfl_xor(pb[s], m);
            #pragma unroll
            for (int k = 0; k < 8; ++k) pa[s][k] += __shfl_xor(pa[s][k], m);
        }
    }

    const int wv = tid >> 6, lane = tid & 63;
    if (lane < 4) {
        #pragma unroll
        for (int s = 0; s < 4; ++s)
            #pragma unroll
            for (int k = 0; k < 8; ++k) ls_pa[wv][s][lane * 8 + k] = pa[s][k];
        if (lane == 0) {
            #pragma unroll
            for (int s = 0; s < 4; ++s) { ls_pb[wv][s] = pb[s]; ls_ps[wv][s] = ps[s]; }
        }
    }
    __syncthreads();
    if (tid < 128) {
        const int s = tid >> 5, d = tid & 31;
        float a = ls_pa[0][s][d] + ls_pa[1][s][d] + ls_pa[2][s][d] + ls_pa[3][s][d];
        pa_cur[(((size_t)b * Cn + c) * Sn + s) * Dn + d] = a;
        if (d == 0) {
            pb_cur[((size_t)b * Cn + c) * Sn + s] =
                ls_pb[0][s] + ls_pb[1][s] + ls_pb[2][s] + ls_pb[3][s];
            ps_cur[((size_t)b * Cn + c) * Sn + s] =
                ls_ps[0][s] + ls_ps[1][s] + ls_ps[2][s] + ls_ps[3][s];
        }
    }
}

// ---------------------------------------------------------------------------
__global__ __launch_bounds__(128)
void final_k(const float* __restrict__ lnx_g, const float* __restrict__ lnx_b,
             const float* __restrict__ Wv,
             const float* __restrict__ Wih, const float* __restrict__ Whh,
             const float* __restrict__ bih, const float* __restrict__ bhh,
             const float* __restrict__ W1, const float* __restrict__ b1v,
             const float* __restrict__ W2, const float* __restrict__ b2v,
             const float* __restrict__ lns_g, const float* __restrict__ lns_b,
             const float* __restrict__ lnff_g, const float* __restrict__ lnff_b,
             const float* __restrict__ Wq, const float* __restrict__ Wk,
             const float* __restrict__ slots_prev,
             const float* __restrict__ pa_prev, const float* __restrict__ pb_prev,
             const float* __restrict__ ps_prev,
             float* __restrict__ out)
{
    const int b = blockIdx.x, tid = threadIdx.x;
    __shared__ float qt_sh[Sn][Dn], ta[Sn][Dn], tb[Sn][Dn];
    chain_fn<1, 0>(b, tid, pa_prev, pb_prev, ps_prev, slots_prev,
        nullptr, nullptr, nullptr, lnx_g, lnx_b,
        Wv, Wih, Whh, bih, bhh, W1, b1v, W2, b2v,
        lns_g, lns_b, lnff_g, lnff_b, Wq, Wk, qt_sh, ta, tb, out);
}

// ---------------------------------------------------------------------------
// Fallback: proven single fused kernel (round 3, 163 us) if ws is too small.
// ---------------------------------------------------------------------------
#define TPB 1024
#define NW (TPB / 64)
#define RPS (TPB / 4)
#define STEPS (Nn / RPS)

__global__ __launch_bounds__(TPB)
void slot_fused(const float* __restrict__ x, const float* __restrict__ noise,
                const float* __restrict__ mu, const float* __restrict__ logsig,
                const float* __restrict__ Wq, const float* __restrict__ Wk,
                const float* __restrict__ Wv,
                const float* __restrict__ Wih, const float* __restrict__ Whh,
                const float* __restrict__ bih, const float* __restrict__ bhh,
                const float* __restrict__ W1, const float* __restrict__ b1v,
                const float* __restrict__ W2, const float* __restrict__ b2v,
                const float* __restrict__ lnx_g, const float* __restrict__ lnx_b,
                const float* __restrict__ lns_g, const float* __restrict__ lns_b,
                const float* __restrict__ lnff_g, const float* __restrict__ lnff_b,
                float* __restrict__ out)
{
    const int b   = blockIdx.x;
    const int tid = threadIdx.x;
    __shared__ float slots_sh[Sn][Dn];
    __shared__ float qt_sh[Sn][Dn];
    __shared__ float a_sh[Sn][Dn];
    __shared__ float b_sh[Sn][Dn];
    __shared__ float h_sh[Sn][Dn];
    __shared__ float ls_u[NW][Sn][Dn];
    __shared__ float ls_s[NW][Sn];
    const int s128 = tid >> 5, d128 = tid & 31;

    if (tid < 128) {
        float sv = mu[d128] + noise[(b * Sn + s128) * Dn + d128] * __expf(logsig[d128]);
        slots_sh[s128][d128] = sv;
        float sx = sv, sxx = sv * sv;
        #pragma unroll
        for (int m = 1; m <= 16; m <<= 1) { sx += __shfl_xor(sx, m); sxx += __shfl_xor(sxx, m); }
        float mean = sx * (1.0f / 32.0f);
        float var  = sxx * (1.0f / 32.0f) - mean * mean;
        a_sh[s128][d128] = (sv - mean) * rsqrtf(var + 1e-5f) * lns_g[d128] + lns_b[d128];
    }
    __syncthreads();
    if (tid < 128) {
        float q = 0.f;
        #pragma unroll 8
        for (int j = 0; j < 32; ++j) q = fmaf(Wq[d128 * 32 + j], a_sh[s128][j], q);
        b_sh[s128][d128] = q;
    }
    __syncthreads();
    if (tid < 128) {
        float qv = 0.f;
        #pragma unroll 8
        for (int i = 0; i < 32; ++i) qv = fmaf(b_sh[s128][i], Wk[i * 32 + d128], qv);
        qt_sh[s128][d128] = qv * SCALE;
    }
    __syncthreads();

    const int sub = tid & 3, col0 = sub * 8;
    const int rg  = tid >> 2;
    float g_r[8], e_r[8];
    #pragma unroll
    for (int k = 0; k < 8; ++k) { g_r[k] = lnx_g[col0 + k]; e_r[k] = lnx_b[col0 + k]; }
    const float* xb = x + (size_t)b * Nn * Dn;
    float sv_reg = 0.f;

    for (int it = 0; it < 3; ++it) {
        float qt_r[4][8];
        #pragma unroll
        for (int s = 0; s < 4; ++s)
            #pragma unroll
            for (int k = 0; k < 8; ++k) qt_r[s][k] = qt_sh[s][col0 + k];
        float pu[4][8];
        float ps[4] = {0.f, 0.f, 0.f, 0.f};
        #pragma unroll
        for (int s = 0; s < 4; ++s)
            #pragma unroll
            for (int k = 0; k < 8; ++k) pu[s][k] = 0.f;

        const float* xr0 = xb + (size_t)rg * Dn + col0;
        float4 v0 = *(const float4*)(xr0);
        float4 v1 = *(const float4*)(xr0 + 4);
        #pragma unroll 2
        for (int t = 0; t < STEPS; ++t) {
            const float* xrn = xb + (size_t)((((t + 1) & (STEPS - 1)) * RPS) + rg) * Dn + col0;
            float4 n0 = *(const float4*)(xrn);
            float4 n1 = *(const float4*)(xrn + 4);
            float xv[8] = {v0.x, v0.y, v0.z, v0.w, v1.x, v1.y, v1.z, v1.w};
            float sx = 0.f, sxx = 0.f;
            #pragma unroll
            for (int k = 0; k < 8; ++k) { sx += xv[k]; sxx = fmaf(xv[k], xv[k], sxx); }
            sx += __shfl_xor(sx, 1); sxx += __shfl_xor(sxx, 1);
            sx += __shfl_xor(sx, 2); sxx += __shfl_xor(sxx, 2);
            float mean = sx * (1.0f / 32.0f);
            float var  = sxx * (1.0f / 32.0f) - mean * mean;
            float rs   = rsqrtf(var + 1e-5f);
            float xn[8];
            #pragma unroll
            for (int k = 0; k < 8; ++k) xn[k] = fmaf((xv[k] - mean) * rs, g_r[k], e_r[k]);
            #pragma unroll
            for (int s = 0; s < 4; ++s) {
                float a = 0.f;
                #pragma unroll
                for (int k = 0; k < 8; ++k) a = fmaf(xn[k], qt_r[s][k], a);
                a += __shfl_xor(a, 1);
                a += __shfl_xor(a, 2);
                float w = __expf(a);
                ps[s] += w;
                #pragma unroll
                for (int k = 0; k < 8; ++k) pu[s][k] = fmaf(w, xn[k], pu[s][k]);
            }
            v0 = n0; v1 = n1;
        }
        #pragma unroll
        for (int m = 4; m <= 32; m <<= 1) {
            #pragma unroll
            for (int s = 0; s < 4; ++s) {
                ps[s] += __shfl_xor(ps[s], m);
                #pragma unroll
                for (int k = 0; k < 8; ++k) pu[s][k] += __shfl_xor(pu[s][k], m);
            }
        }
        {
            const int wv = tid >> 6, lane = tid & 63;
            if (lane < 4) {
                #pragma unroll
                for (int s = 0; s < 4; ++s)
                    #pragma unroll
                    for (int k = 0; k < 8; ++k) ls_u[wv][s][lane * 8 + k] = pu[s][k];
                if (lane == 0) {
                    #pragma unroll
                    for (int s = 0; s < 4; ++s) ls_s[wv][s] = ps[s];
                }
            }
        }
        __syncthreads();
        if (tid < 128) {
            float u = 0.f, ss = 0.f;
            #pragma unroll
            for (int w = 0; w < NW; ++w) { u += ls_u[w][s128][d128]; ss += ls_s[w][s128]; }
            a_sh[s128][d128] = (u / ss) * RENORM;
        }
        __syncthreads();
        if (tid < 128) {
            float upd = 0.f;
            #pragma unroll 8
            for (int j = 0; j < 32; ++j) upd = fmaf(Wv[d128 * 32 + j], a_sh[s128][j], upd);
            b_sh[s128][d128] = upd;
        }
        __syncthreads();
        if (tid < 128) {
            float gi[3], gh[3];
            #pragma unroll
            for (int g3 = 0; g3 < 3; ++g3) {
                const int row = g3 * 32 + d128;
                float a1 = bih[row], a2 = bhh[row];
                #pragma unroll 8
                for (int j = 0; j < 32; ++j) {
                    a1 = fmaf(Wih[row * 32 + j], b_sh[s128][j], a1);
                    a2 = fmaf(Whh[row * 32 + j], slots_sh[s128][j], a2);
                }
                gi[g3] = a1; gh[g3] = a2;
            }
            float r  = sigmoidf_(gi[0] + gh[0]);
            float z  = sigmoidf_(gi[1] + gh[1]);
            float nn = tanhf(gi[2] + r * gh[2]);
            sv_reg = (1.0f - z) * nn + z * slots_sh[s128][d128];
            float sx = sv_reg, sxx = sv_reg * sv_reg;
            #pragma unroll
            for (int m = 1; m <= 16; m <<= 1) { sx += __shfl_xor(sx, m); sxx += __shfl_xor(sxx, m); }
            float mean = sx * (1.0f / 32.0f);
            float var  = sxx * (1.0f / 32.0f) - mean * mean;
            a_sh[s128][d128] = (sv_reg - mean) * rsqrtf(var + 1e-5f) * lnff_g[d128] + lnff_b[d128];
        }
        __syncthreads();
        if (tid < 128) {
            float h = b1v[d128];
            #pragma unroll 8
            for (int j = 0; j < 32; ++j) h = fmaf(W1[d128 * 32 + j], a_sh[s128][j], h);
            h_sh[s128][d128] = fmaxf(h, 0.f);
        }
        __syncthreads();
        if (tid < 128) {
            float o = b2v[d128];
            #pragma unroll 8
            for (int j = 0; j < 32; ++j) o = fmaf(W2[d128 * 32 + j], h_sh[s128][j], o);
            float sfin = sv_reg + o;
            slots_sh[s128][d128] = sfin;
            if (it < 2) {
                float sx = sfin, sxx = sfin * sfin;
                #pragma unroll
                for (int m = 1; m <= 16; m <<= 1) { sx += __shfl_xor(sx, m); sxx += __shfl_xor(sxx, m); }
                float mean = sx * (1.0f / 32.0f);
                float var  = sxx * (1.0f / 32.0f) - mean * mean;
                a_sh[s128][d128] = (sfin - mean) * rsqrtf(var + 1e-5f) * lns_g[d128] + lns_b[d128];
            }
        }
        __syncthreads();
        if (it < 2) {
            if (tid < 128) {
                float q = 0.f;
                #pragma unroll 8
                for (int j = 0; j < 32; ++j) q = fmaf(Wq[d128 * 32 + j], a_sh[s128][j], q);
                b_sh[s128][d128] = q;
            }
            __syncthreads();
            if (tid < 128) {
                float qv = 0.f;
                #pragma unroll 8
                for (int i = 0; i < 32; ++i) qv = fmaf(b_sh[s128][i], Wk[i * 32 + d128], qv);
                qt_sh[s128][d128] = qv * SCALE;
            }
            __syncthreads();
        }
    }
    if (tid < 128)
        out[(size_t)b * 128 + tid] = slots_sh[s128][d128];
}

// ---------------------------------------------------------------------------
extern "C" void kernel_launch(void* const* d_in, const int* in_sizes, int n_in,
                              void* d_out, int out_size, void* d_ws, size_t ws_size,
                              hipStream_t stream)
{
    const float* x      = (const float*)d_in[0];
    const float* noise  = (const float*)d_in[1];
    const float* mu     = (const float*)d_in[2];
    const float* logsig = (const float*)d_in[3];
    const float* Wq     = (const float*)d_in[4];
    const float* Wk     = (const float*)d_in[5];
    const float* Wv     = (const float*)d_in[6];
    const float* Wih    = (const float*)d_in[7];
    const float* Whh    = (const float*)d_in[8];
    const float* bih    = (const float*)d_in[9];
    const float* bhh    = (const float*)d_in[10];
    const float* W1     = (const float*)d_in[11];
    const float* b1v    = (const float*)d_in[12];
    const float* W2     = (const float*)d_in[13];
    const float* b2v    = (const float*)d_in[14];
    const float* lnx_g  = (const float*)d_in[15];
    const float* lnx_b  = (const float*)d_in[16];
    const float* lns_g  = (const float*)d_in[17];
    const float* lns_b  = (const float*)d_in[18];
    const float* lnff_g = (const float*)d_in[19];
    const float* lnff_b = (const float*)d_in[20];
    float* out = (float*)d_out;

    if (ws_size >= WS_REQ) {
        float* wsf    = (float*)d_ws;
        float* slots0 = wsf;
        float* slots1 = slots0 + Bn * Sn * Dn;
        float* slots2 = slots1 + Bn * Sn * Dn;
        float* pa0    = slots2 + Bn * Sn * Dn;
        float* pa1    = pa0 + Bn * Cn * Sn * Dn;
        float* pa2    = pa1 + Bn * Cn * Sn * Dn;
        float* pb0    = pa2 + Bn * Cn * Sn * Dn;
        float* pb1    = pb0 + Bn * Cn * Sn;
        float* pb2    = pb1 + Bn * Cn * Sn;
        float* ps0    = pb2 + Bn * Cn * Sn;
        float* ps1    = ps0 + Bn * Cn * Sn;
        float* ps2    = ps1 + Bn * Cn * Sn;

        pass_k<0><<<dim3(Cn, Bn), PT, 0, stream>>>(x, noise, mu, logsig,
            Wq, Wk, Wv, Wih, Whh, bih, bhh, W1, b1v, W2, b2v,
            lnx_g, lnx_b, lns_g, lns_b, lnff_g, lnff_b,
            nullptr, slots0, nullptr, nullptr, nullptr, pa0, pb0, ps0);
        pass_k<1><<<dim3(Cn, Bn), PT, 0, stream>>>(x, noise, mu, logsig,
            Wq, Wk, Wv, Wih, Whh, bih, bhh, W1, b1v, W2, b2v,
            lnx_g, lnx_b, lns_g, lns_b, lnff_g, lnff_b,
            slots0, slots1, pa0, pb0, ps0, pa1, pb1, ps1);
        pass_k<2><<<dim3(Cn, Bn), PT, 0, stream>>>(x, noise, mu, logsig,
            Wq, Wk, Wv, Wih, Whh, bih, bhh, W1, b1v, W2, b2v,
            lnx_g, lnx_b, lns_g, lns_b, lnff_g, lnff_b,
            slots1, slots2, pa1, pb1, ps1, pa2, pb2, ps2);
        final_k<<<Bn, 128, 0, stream>>>(lnx_g, lnx_b, Wv, Wih, Whh, bih, bhh,
            W1, b1v, W2, b2v, lns_g, lns_b, lnff_g, lnff_b, Wq, Wk,
            slots2, pa2, pb2, ps2, out);
    } else {
        slot_fused<<<Bn, TPB, 0, stream>>>(x, noise, mu, logsig, Wq, Wk, Wv,
                                           Wih, Whh, bih, bhh, W1, b1v, W2, b2v,
                                           lnx_g, lnx_b, lns_g, lns_b, lnff_g, lnff_b,
                                           out);
    }
}

// Round 14
// 115.431 us; speedup vs baseline: 2.3386x; 2.3386x over previous
//
#include <hip/hip_runtime.h>
#include <hip/hip_bf16.h>

// SlotAttention: B=128, N=8192, S=4, D=32, ITERS=3.  Output dtype: float32.
//
// Round-11 proven skeleton (7 launches: init -> 3x{pass; update}; DPP
// quad-perm reductions; prefetch-2; Cn=16; NO per-block chain prologue --
// round-13 showed the prologue costs ~5us/block) + bf16 y-cache:
//   pass0: read x fp32, write y = LN(x) bf16, accumulate it-0 partials.
//   pass12: read y bf16 (64 MB, L3-resident), accumulate partials.
//   update: combine -> Wv -> GRU -> LNff -> MLP -> slots/qt/out.
// u = sum w*y directly (y pre-normalized); logits = qt . y.

#define Bn 128
#define Nn 8192
#define Sn 4
#define Dn 32
#define SCALE 0.17677669529663687f  // D^-0.5
#define RENORM (1.0f / (1.0f + (float)Nn * 1e-8f))

#define Cn 16                 // chunks per batch
#define RPB (Nn / Cn)         // 512 rows per pass-block
#define PT 256                // pass threads (4 waves)
#define RSTEP (PT / 4)        // 64 rows per step (4 lanes per row)
#define NSTEP (RPB / RSTEP)   // 8 steps

#define WS_REQ ((size_t)(16384 + 16384 + Bn*Cn*Sn*Dn + Bn*Cn*Sn) * 4 + (size_t)Bn * Nn * Dn * 2)

__device__ __forceinline__ float sigmoidf_(float v) { return 1.0f / (1.0f + __expf(-v)); }

// DPP cross-lane add within each quad (VALU pipe, no LDS latency).
template<int CTRL>
__device__ __forceinline__ float dpp_xadd(float v) {
    int p = __builtin_amdgcn_update_dpp(0, __float_as_int(v), CTRL, 0xF, 0xF, true);
    return v + __int_as_float(p);
}
#define DPP_X1 0xB1
#define DPP_X2 0x4E

__device__ __forceinline__ unsigned f2bf_rne(float f) {
    unsigned u = __float_as_uint(f);
    u += 0x7fffu + ((u >> 16) & 1u);
    return u >> 16;
}
__device__ __forceinline__ float bflo2f(unsigned u) { return __uint_as_float(u << 16); }
__device__ __forceinline__ float bfhi2f(unsigned u) { return __uint_as_float(u & 0xffff0000u); }

// ---------------------------------------------------------------------------
// init: slots = mu + noise*exp(logsigma); qt = scale * (LN_s(slots) @ Wq.T) @ Wk
// ---------------------------------------------------------------------------
__global__ __launch_bounds__(128)
void init_kernel(const float* __restrict__ noise, const float* __restrict__ mu,
                 const float* __restrict__ logsig,
                 const float* __restrict__ lns_g, const float* __restrict__ lns_b,
                 const float* __restrict__ Wq, const float* __restrict__ Wk,
                 float* __restrict__ slots, float* __restrict__ qt)
{
    const int b = blockIdx.x;
    const int tid = threadIdx.x;
    const int s = tid >> 5, d = tid & 31;
    __shared__ float sh_a[4][32];
    __shared__ float sh_b[4][32];

    float sv = mu[d] + noise[(b * Sn + s) * Dn + d] * __expf(logsig[d]);
    slots[(b * Sn + s) * Dn + d] = sv;

    float sx = sv, sxx = sv * sv;
    #pragma unroll
    for (int m = 1; m <= 16; m <<= 1) { sx += __shfl_xor(sx, m); sxx += __shfl_xor(sxx, m); }
    float mean = sx * (1.0f / 32.0f);
    float var  = sxx * (1.0f / 32.0f) - mean * mean;
    sh_a[s][d] = (sv - mean) * rsqrtf(var + 1e-5f) * lns_g[d] + lns_b[d];
    __syncthreads();

    float q = 0.0f;
    #pragma unroll 8
    for (int j = 0; j < 32; ++j) q = fmaf(Wq[d * 32 + j], sh_a[s][j], q);
    sh_b[s][d] = q;
    __syncthreads();

    float qtv = 0.0f;
    #pragma unroll 8
    for (int i = 0; i < 32; ++i) qtv = fmaf(sh_b[s][i], Wk[i * 32 + d], qtv);
    qt[(b * Sn + s) * Dn + d] = qtv * SCALE;
}

// ---------------------------------------------------------------------------
// shared epilogue: wave butterfly + LDS combine + partial store
// ---------------------------------------------------------------------------
__device__ __forceinline__ void pass_epilogue(
    int b, int c, int tid, float pa[4][8], float ps[4],
    float (*ls_pa)[Sn][Dn], float (*ls_ps)[Sn],
    float* __restrict__ pa_out, float* __restrict__ ps_out)
{
    #pragma unroll
    for (int m = 4; m <= 32; m <<= 1) {
        #pragma unroll
        for (int s = 0; s < 4; ++s) {
            ps[s] += __shfl_xor(ps[s], m);
            #pragma unroll
            for (int k = 0; k < 8; ++k) pa[s][k] += __shfl_xor(pa[s][k], m);
        }
    }
    const int wv = tid >> 6, lane = tid & 63;
    if (lane < 4) {
        #pragma unroll
        for (int s = 0; s < 4; ++s)
            #pragma unroll
            for (int k = 0; k < 8; ++k) ls_pa[wv][s][lane * 8 + k] = pa[s][k];
        if (lane == 0) {
            #pragma unroll
            for (int s = 0; s < 4; ++s) ls_ps[wv][s] = ps[s];
        }
    }
    __syncthreads();
    if (tid < 128) {
        const int s = tid >> 5, d = tid & 31;
        float a = ls_pa[0][s][d] + ls_pa[1][s][d] + ls_pa[2][s][d] + ls_pa[3][s][d];
        pa_out[(((size_t)b * Cn + c) * Sn + s) * Dn + d] = a;
        if (d == 0)
            ps_out[((size_t)b * Cn + c) * Sn + s] =
                ls_ps[0][s] + ls_ps[1][s] + ls_ps[2][s] + ls_ps[3][s];
    }
}

// ---------------------------------------------------------------------------
// pass0: read x fp32, compute y = LN(x), write y bf16, accumulate partials.
// DPP reductions, prefetch-2.
// ---------------------------------------------------------------------------
__global__ __launch_bounds__(PT)
void pass0_kernel(const float* __restrict__ x, unsigned short* __restrict__ y,
                  const float* __restrict__ qt,
                  const float* __restrict__ lnx_g, const float* __restrict__ lnx_b,
                  float* __restrict__ part_pa, float* __restrict__ part_ps)
{
    const int c = blockIdx.x;
    const int b = blockIdx.y;
    const int tid = threadIdx.x;
    const int sub = tid & 3, col0 = sub * 8;
    const int rg  = tid >> 2;

    float qt_r[4][8], g_r[8], e_r[8];
    {
        const float* qtb = qt + (size_t)b * Sn * Dn;
        #pragma unroll
        for (int k = 0; k < 8; ++k) { g_r[k] = lnx_g[col0 + k]; e_r[k] = lnx_b[col0 + k]; }
        #pragma unroll
        for (int s = 0; s < 4; ++s)
            #pragma unroll
            for (int k = 0; k < 8; ++k) qt_r[s][k] = qtb[s * Dn + col0 + k];
    }

    float pa[4][8], ps[4] = {0.f,0.f,0.f,0.f};
    #pragma unroll
    for (int s = 0; s < 4; ++s)
        #pragma unroll
        for (int k = 0; k < 8; ++k) pa[s][k] = 0.f;

    const float* xb = x + ((size_t)b * Nn + (size_t)c * RPB) * Dn;
    unsigned short* yb = y + ((size_t)b * Nn + (size_t)c * RPB) * Dn;
    const float* base = xb + (size_t)rg * Dn + col0;

    float4 v0  = *(const float4*)(base);
    float4 v1  = *(const float4*)(base + 4);
    float4 n10 = *(const float4*)(base + (size_t)RSTEP * Dn);
    float4 n11 = *(const float4*)(base + (size_t)RSTEP * Dn + 4);

    for (int t = 0; t < NSTEP; ++t) {
        const int t2 = (t + 2 < NSTEP) ? t + 2 : NSTEP - 1;
        const float* p2 = base + (size_t)(t2 * RSTEP) * Dn;
        float4 n20 = *(const float4*)(p2);
        float4 n21 = *(const float4*)(p2 + 4);

        float xv[8] = {v0.x, v0.y, v0.z, v0.w, v1.x, v1.y, v1.z, v1.w};

        float sx = 0.f, sxx = 0.f;
        #pragma unroll
        for (int k = 0; k < 8; ++k) { sx += xv[k]; sxx = fmaf(xv[k], xv[k], sxx); }
        sx  = dpp_xadd<DPP_X1>(sx);   sx  = dpp_xadd<DPP_X2>(sx);
        sxx = dpp_xadd<DPP_X1>(sxx);  sxx = dpp_xadd<DPP_X2>(sxx);
        float mean = sx * (1.0f / 32.0f);
        float var  = sxx * (1.0f / 32.0f) - mean * mean;
        float rs   = rsqrtf(var + 1e-5f);

        float xn[8];
        #pragma unroll
        for (int k = 0; k < 8; ++k) xn[k] = fmaf((xv[k] - mean) * rs, g_r[k], e_r[k]);

        uint4 yw;
        yw.x = (f2bf_rne(xn[1]) << 16) | f2bf_rne(xn[0]);
        yw.y = (f2bf_rne(xn[3]) << 16) | f2bf_rne(xn[2]);
        yw.z = (f2bf_rne(xn[5]) << 16) | f2bf_rne(xn[4]);
        yw.w = (f2bf_rne(xn[7]) << 16) | f2bf_rne(xn[6]);
        *(uint4*)(yb + (size_t)(t * RSTEP + rg) * Dn + col0) = yw;

        float ds[4] = {0.f,0.f,0.f,0.f};
        #pragma unroll
        for (int k = 0; k < 8; ++k)
            #pragma unroll
            for (int s = 0; s < 4; ++s) ds[s] = fmaf(xn[k], qt_r[s][k], ds[s]);
        #pragma unroll
        for (int s = 0; s < 4; ++s) {
            ds[s] = dpp_xadd<DPP_X1>(ds[s]);
            ds[s] = dpp_xadd<DPP_X2>(ds[s]);
        }
        #pragma unroll
        for (int s = 0; s < 4; ++s) {
            float w = __expf(ds[s]);            // |logit| <~ 8 -> safe
            ps[s] += w;
            #pragma unroll
            for (int k = 0; k < 8; ++k) pa[s][k] = fmaf(w, xn[k], pa[s][k]);
        }
        v0 = n10; v1 = n11; n10 = n20; n11 = n21;
    }

    __shared__ float ls_pa[4][Sn][Dn];
    __shared__ float ls_ps[4][Sn];
    pass_epilogue(b, c, tid, pa, ps, ls_pa, ls_ps, part_pa, part_ps);
}

// ---------------------------------------------------------------------------
// pass12: read y bf16 (L3-resident), accumulate partials. DPP, prefetch-2.
// ---------------------------------------------------------------------------
__global__ __launch_bounds__(PT)
void pass12_kernel(const unsigned short* __restrict__ y, const float* __restrict__ qt,
                   float* __restrict__ part_pa, float* __restrict__ part_ps)
{
    const int c = blockIdx.x;
    const int b = blockIdx.y;
    const int tid = threadIdx.x;
    const int sub = tid & 3, col0 = sub * 8;
    const int rg  = tid >> 2;

    float qt_r[4][8];
    {
        const float* qtb = qt + (size_t)b * Sn * Dn;
        #pragma unroll
        for (int s = 0; s < 4; ++s)
            #pragma unroll
            for (int k = 0; k < 8; ++k) qt_r[s][k] = qtb[s * Dn + col0 + k];
    }

    float pa[4][8], ps[4] = {0.f,0.f,0.f,0.f};
    #pragma unroll
    for (int s = 0; s < 4; ++s)
        #pragma unroll
        for (int k = 0; k < 8; ++k) pa[s][k] = 0.f;

    const unsigned short* yb = y + ((size_t)b * Nn + (size_t)c * RPB) * Dn;
    const unsigned short* base = yb + (size_t)rg * Dn + col0;

    uint4 v  = *(const uint4*)(base);
    uint4 n1 = *(const uint4*)(base + (size_t)RSTEP * Dn);

    for (int t = 0; t < NSTEP; ++t) {
        const int t2 = (t + 2 < NSTEP) ? t + 2 : NSTEP - 1;
        uint4 n2 = *(const uint4*)(base + (size_t)(t2 * RSTEP) * Dn);

        float yv[8];
        yv[0] = bflo2f(v.x); yv[1] = bfhi2f(v.x);
        yv[2] = bflo2f(v.y); yv[3] = bfhi2f(v.y);
        yv[4] = bflo2f(v.z); yv[5] = bfhi2f(v.z);
        yv[6] = bflo2f(v.w); yv[7] = bfhi2f(v.w);

        float ds[4] = {0.f,0.f,0.f,0.f};
        #pragma unroll
        for (int k = 0; k < 8; ++k)
            #pragma unroll
            for (int s = 0; s < 4; ++s) ds[s] = fmaf(yv[k], qt_r[s][k], ds[s]);
        #pragma unroll
        for (int s = 0; s < 4; ++s) {
            ds[s] = dpp_xadd<DPP_X1>(ds[s]);
            ds[s] = dpp_xadd<DPP_X2>(ds[s]);
        }
        #pragma unroll
        for (int s = 0; s < 4; ++s) {
            float w = __expf(ds[s]);
            ps[s] += w;
            #pragma unroll
            for (int k = 0; k < 8; ++k) pa[s][k] = fmaf(w, yv[k], pa[s][k]);
        }
        v = n1; n1 = n2;
    }

    __shared__ float ls_pa[4][Sn][Dn];
    __shared__ float ls_ps[4][Sn];
    pass_epilogue(b, c, tid, pa, ps, ls_pa, ls_ps, part_pa, part_ps);
}

// ---------------------------------------------------------------------------
// update: ubar = (PA/PS)*renorm -> Wv -> GRU -> LNff -> MLP -> slots/qt/out.
// ---------------------------------------------------------------------------
__global__ __launch_bounds__(128)
void update_kernel(const float* __restrict__ part_pa, const float* __restrict__ part_ps,
                   const float* __restrict__ Wv,
                   const float* __restrict__ Wih, const float* __restrict__ Whh,
                   const float* __restrict__ bih, const float* __restrict__ bhh,
                   const float* __restrict__ W1, const float* __restrict__ b1v,
                   const float* __restrict__ W2, const float* __restrict__ b2v,
                   const float* __restrict__ lns_g, const float* __restrict__ lns_b,
                   const float* __restrict__ lnff_g, const float* __restrict__ lnff_b,
                   const float* __restrict__ Wq, const float* __restrict__ Wk,
                   float* __restrict__ slots, float* __restrict__ qt,
                   float* __restrict__ out, int write_out, int write_qt)
{
    const int b = blockIdx.x;
    const int tid = threadIdx.x;
    const int s = tid >> 5, d = tid & 31;
    __shared__ float sh_a[4][32];
    __shared__ float sh_b[4][32];
    __shared__ float sh_sold[4][32];
    __shared__ float sh_h[4][32];

    float PA = 0.f, PS = 0.f;
    #pragma unroll
    for (int c = 0; c < Cn; ++c) {
        PA += part_pa[(((size_t)b * Cn + c) * Sn + s) * Dn + d];
        PS += part_ps[((size_t)b * Cn + c) * Sn + s];
    }
    sh_a[s][d] = (PA / PS) * RENORM;
    float sold = slots[(b * Sn + s) * Dn + d];
    sh_sold[s][d] = sold;
    __syncthreads();

    float upd = 0.f;
    #pragma unroll 8
    for (int j = 0; j < 32; ++j) upd = fmaf(Wv[d * 32 + j], sh_a[s][j], upd);
    sh_b[s][d] = upd;
    __syncthreads();

    float gi[3], gh[3];
    #pragma unroll
    for (int g3 = 0; g3 < 3; ++g3) {
        const int row = g3 * 32 + d;
        float a1 = bih[row], a2 = bhh[row];
        #pragma unroll 8
        for (int j = 0; j < 32; ++j) {
            a1 = fmaf(Wih[row * 32 + j], sh_b[s][j], a1);
            a2 = fmaf(Whh[row * 32 + j], sh_sold[s][j], a2);
        }
        gi[g3] = a1; gh[g3] = a2;
    }
    float r  = sigmoidf_(gi[0] + gh[0]);
    float z  = sigmoidf_(gi[1] + gh[1]);
    float nn = tanhf(gi[2] + r * gh[2]);
    float sv = (1.0f - z) * nn + z * sold;

    {
        float sx = sv, sxx = sv * sv;
        #pragma unroll
        for (int m = 1; m <= 16; m <<= 1) { sx += __shfl_xor(sx, m); sxx += __shfl_xor(sxx, m); }
        float mean = sx * (1.0f / 32.0f);
        float var  = sxx * (1.0f / 32.0f) - mean * mean;
        float rs   = rsqrtf(var + 1e-5f);
        __syncthreads();
        sh_a[s][d] = (sv - mean) * rs * lnff_g[d] + lnff_b[d];
    }
    __syncthreads();

    float h1 = b1v[d];
    #pragma unroll 8
    for (int j = 0; j < 32; ++j) h1 = fmaf(W1[d * 32 + j], sh_a[s][j], h1);
    sh_h[s][d] = fmaxf(h1, 0.0f);
    __syncthreads();

    float o = b2v[d];
    #pragma unroll 8
    for (int j = 0; j < 32; ++j) o = fmaf(W2[d * 32 + j], sh_h[s][j], o);
    float sfin = sv + o;

    slots[(b * Sn + s) * Dn + d] = sfin;
    if (write_out) out[(b * Sn + s) * Dn + d] = sfin;

    if (write_qt) {
        float sx = sfin, sxx = sfin * sfin;
        #pragma unroll
        for (int m = 1; m <= 16; m <<= 1) { sx += __shfl_xor(sx, m); sxx += __shfl_xor(sxx, m); }
        float mean = sx * (1.0f / 32.0f);
        float var  = sxx * (1.0f / 32.0f) - mean * mean;
        float rs   = rsqrtf(var + 1e-5f);
        __syncthreads();
        sh_a[s][d] = (sfin - mean) * rs * lns_g[d] + lns_b[d];
        __syncthreads();
        float q = 0.f;
        #pragma unroll 8
        for (int j = 0; j < 32; ++j) q = fmaf(Wq[d * 32 + j], sh_a[s][j], q);
        sh_b[s][d] = q;
        __syncthreads();
        float qtv = 0.f;
        #pragma unroll 8
        for (int i = 0; i < 32; ++i) qtv = fmaf(sh_b[s][i], Wk[i * 32 + d], qtv);
        qt[(b * Sn + s) * Dn + d] = qtv * SCALE;
    }
}

// ---------------------------------------------------------------------------
// Fallback: proven single fused kernel (round 3, 163 us) in case ws is small.
// ---------------------------------------------------------------------------
#define TPB 1024
#define NW (TPB / 64)
#define RPS (TPB / 4)
#define STEPS (Nn / RPS)

__global__ __launch_bounds__(TPB)
void slot_fused(const float* __restrict__ x, const float* __restrict__ noise,
                const float* __restrict__ mu, const float* __restrict__ logsig,
                const float* __restrict__ Wq, const float* __restrict__ Wk,
                const float* __restrict__ Wv,
                const float* __restrict__ Wih, const float* __restrict__ Whh,
                const float* __restrict__ bih, const float* __restrict__ bhh,
                const float* __restrict__ W1, const float* __restrict__ b1v,
                const float* __restrict__ W2, const float* __restrict__ b2v,
                const float* __restrict__ lnx_g, const float* __restrict__ lnx_b,
                const float* __restrict__ lns_g, const float* __restrict__ lns_b,
                const float* __restrict__ lnff_g, const float* __restrict__ lnff_b,
                float* __restrict__ out)
{
    const int b   = blockIdx.x;
    const int tid = threadIdx.x;
    __shared__ float slots_sh[Sn][Dn];
    __shared__ float qt_sh[Sn][Dn];
    __shared__ float a_sh[Sn][Dn];
    __shared__ float b_sh[Sn][Dn];
    __shared__ float h_sh[Sn][Dn];
    __shared__ float ls_u[NW][Sn][Dn];
    __shared__ float ls_s[NW][Sn];
    const int s128 = tid >> 5, d128 = tid & 31;

    if (tid < 128) {
        float sv = mu[d128] + noise[(b * Sn + s128) * Dn + d128] * __expf(logsig[d128]);
        slots_sh[s128][d128] = sv;
        float sx = sv, sxx = sv * sv;
        #pragma unroll
        for (int m = 1; m <= 16; m <<= 1) { sx += __shfl_xor(sx, m); sxx += __shfl_xor(sxx, m); }
        float mean = sx * (1.0f / 32.0f);
        float var  = sxx * (1.0f / 32.0f) - mean * mean;
        a_sh[s128][d128] = (sv - mean) * rsqrtf(var + 1e-5f) * lns_g[d128] + lns_b[d128];
    }
    __syncthreads();
    if (tid < 128) {
        float q = 0.f;
        #pragma unroll 8
        for (int j = 0; j < 32; ++j) q = fmaf(Wq[d128 * 32 + j], a_sh[s128][j], q);
        b_sh[s128][d128] = q;
    }
    __syncthreads();
    if (tid < 128) {
        float qv = 0.f;
        #pragma unroll 8
        for (int i = 0; i < 32; ++i) qv = fmaf(b_sh[s128][i], Wk[i * 32 + d128], qv);
        qt_sh[s128][d128] = qv * SCALE;
    }
    __syncthreads();

    const int sub = tid & 3, col0 = sub * 8;
    const int rg  = tid >> 2;
    float g_r[8], e_r[8];
    #pragma unroll
    for (int k = 0; k < 8; ++k) { g_r[k] = lnx_g[col0 + k]; e_r[k] = lnx_b[col0 + k]; }
    const float* xb = x + (size_t)b * Nn * Dn;
    float sv_reg = 0.f;

    for (int it = 0; it < 3; ++it) {
        float qt_r[4][8];
        #pragma unroll
        for (int s = 0; s < 4; ++s)
            #pragma unroll
            for (int k = 0; k < 8; ++k) qt_r[s][k] = qt_sh[s][col0 + k];
        float pu[4][8];
        float ps[4] = {0.f, 0.f, 0.f, 0.f};
        #pragma unroll
        for (int s = 0; s < 4; ++s)
            #pragma unroll
            for (int k = 0; k < 8; ++k) pu[s][k] = 0.f;

        const float* xr0 = xb + (size_t)rg * Dn + col0;
        float4 v0 = *(const float4*)(xr0);
        float4 v1 = *(const float4*)(xr0 + 4);
        #pragma unroll 2
        for (int t = 0; t < STEPS; ++t) {
            const float* xrn = xb + (size_t)((((t + 1) & (STEPS - 1)) * RPS) + rg) * Dn + col0;
            float4 n0 = *(const float4*)(xrn);
            float4 n1 = *(const float4*)(xrn + 4);
            float xv[8] = {v0.x, v0.y, v0.z, v0.w, v1.x, v1.y, v1.z, v1.w};
            float sx = 0.f, sxx = 0.f;
            #pragma unroll
            for (int k = 0; k < 8; ++k) { sx += xv[k]; sxx = fmaf(xv[k], xv[k], sxx); }
            sx += __shfl_xor(sx, 1); sxx += __shfl_xor(sxx, 1);
            sx += __shfl_xor(sx, 2); sxx += __shfl_xor(sxx, 2);
            float mean = sx * (1.0f / 32.0f);
            float var  = sxx * (1.0f / 32.0f) - mean * mean;
            float rs   = rsqrtf(var + 1e-5f);
            float xn[8];
            #pragma unroll
            for (int k = 0; k < 8; ++k) xn[k] = fmaf((xv[k] - mean) * rs, g_r[k], e_r[k]);
            #pragma unroll
            for (int s = 0; s < 4; ++s) {
                float a = 0.f;
                #pragma unroll
                for (int k = 0; k < 8; ++k) a = fmaf(xn[k], qt_r[s][k], a);
                a += __shfl_xor(a, 1);
                a += __shfl_xor(a, 2);
                float w = __expf(a);
                ps[s] += w;
                #pragma unroll
                for (int k = 0; k < 8; ++k) pu[s][k] = fmaf(w, xn[k], pu[s][k]);
            }
            v0 = n0; v1 = n1;
        }
        #pragma unroll
        for (int m = 4; m <= 32; m <<= 1) {
            #pragma unroll
            for (int s = 0; s < 4; ++s) {
                ps[s] += __shfl_xor(ps[s], m);
                #pragma unroll
                for (int k = 0; k < 8; ++k) pu[s][k] += __shfl_xor(pu[s][k], m);
            }
        }
        {
            const int wv = tid >> 6, lane = tid & 63;
            if (lane < 4) {
                #pragma unroll
                for (int s = 0; s < 4; ++s)
                    #pragma unroll
                    for (int k = 0; k < 8; ++k) ls_u[wv][s][lane * 8 + k] = pu[s][k];
                if (lane == 0) {
                    #pragma unroll
                    for (int s = 0; s < 4; ++s) ls_s[wv][s] = ps[s];
                }
            }
        }
        __syncthreads();
        if (tid < 128) {
            float u = 0.f, ss = 0.f;
            #pragma unroll
            for (int w = 0; w < NW; ++w) { u += ls_u[w][s128][d128]; ss += ls_s[w][s128]; }
            a_sh[s128][d128] = (u / ss) * RENORM;
        }
        __syncthreads();
        if (tid < 128) {
            float upd = 0.f;
            #pragma unroll 8
            for (int j = 0; j < 32; ++j) upd = fmaf(Wv[d128 * 32 + j], a_sh[s128][j], upd);
            b_sh[s128][d128] = upd;
        }
        __syncthreads();
        if (tid < 128) {
            float gi[3], gh[3];
            #pragma unroll
            for (int g3 = 0; g3 < 3; ++g3) {
                const int row = g3 * 32 + d128;
                float a1 = bih[row], a2 = bhh[row];
                #pragma unroll 8
                for (int j = 0; j < 32; ++j) {
                    a1 = fmaf(Wih[row * 32 + j], b_sh[s128][j], a1);
                    a2 = fmaf(Whh[row * 32 + j], slots_sh[s128][j], a2);
                }
                gi[g3] = a1; gh[g3] = a2;
            }
            float r  = sigmoidf_(gi[0] + gh[0]);
            float z  = sigmoidf_(gi[1] + gh[1]);
            float nn = tanhf(gi[2] + r * gh[2]);
            sv_reg = (1.0f - z) * nn + z * slots_sh[s128][d128];
            float sx = sv_reg, sxx = sv_reg * sv_reg;
            #pragma unroll
            for (int m = 1; m <= 16; m <<= 1) { sx += __shfl_xor(sx, m); sxx += __shfl_xor(sxx, m); }
            float mean = sx * (1.0f / 32.0f);
            float var  = sxx * (1.0f / 32.0f) - mean * mean;
            a_sh[s128][d128] = (sv_reg - mean) * rsqrtf(var + 1e-5f) * lnff_g[d128] + lnff_b[d128];
        }
        __syncthreads();
        if (tid < 128) {
            float h = b1v[d128];
            #pragma unroll 8
            for (int j = 0; j < 32; ++j) h = fmaf(W1[d128 * 32 + j], a_sh[s128][j], h);
            h_sh[s128][d128] = fmaxf(h, 0.f);
        }
        __syncthreads();
        if (tid < 128) {
            float o = b2v[d128];
            #pragma unroll 8
            for (int j = 0; j < 32; ++j) o = fmaf(W2[d128 * 32 + j], h_sh[s128][j], o);
            float sfin = sv_reg + o;
            slots_sh[s128][d128] = sfin;
            if (it < 2) {
                float sx = sfin, sxx = sfin * sfin;
                #pragma unroll
                for (int m = 1; m <= 16; m <<= 1) { sx += __shfl_xor(sx, m); sxx += __shfl_xor(sxx, m); }
                float mean = sx * (1.0f / 32.0f);
                float var  = sxx * (1.0f / 32.0f) - mean * mean;
                a_sh[s128][d128] = (sfin - mean) * rsqrtf(var + 1e-5f) * lns_g[d128] + lns_b[d128];
            }
        }
        __syncthreads();
        if (it < 2) {
            if (tid < 128) {
                float q = 0.f;
                #pragma unroll 8
                for (int j = 0; j < 32; ++j) q = fmaf(Wq[d128 * 32 + j], a_sh[s128][j], q);
                b_sh[s128][d128] = q;
            }
            __syncthreads();
            if (tid < 128) {
                float qv = 0.f;
                #pragma unroll 8
                for (int i = 0; i < 32; ++i) qv = fmaf(b_sh[s128][i], Wk[i * 32 + d128], qv);
                qt_sh[s128][d128] = qv * SCALE;
            }
            __syncthreads();
        }
    }
    if (tid < 128)
        out[(size_t)b * 128 + tid] = slots_sh[s128][d128];
}

// ---------------------------------------------------------------------------
extern "C" void kernel_launch(void* const* d_in, const int* in_sizes, int n_in,
                              void* d_out, int out_size, void* d_ws, size_t ws_size,
                              hipStream_t stream)
{
    const float* x      = (const float*)d_in[0];
    const float* noise  = (const float*)d_in[1];
    const float* mu     = (const float*)d_in[2];
    const float* logsig = (const float*)d_in[3];
    const float* Wq     = (const float*)d_in[4];
    const float* Wk     = (const float*)d_in[5];
    const float* Wv     = (const float*)d_in[6];
    const float* Wih    = (const float*)d_in[7];
    const float* Whh    = (const float*)d_in[8];
    const float* bih    = (const float*)d_in[9];
    const float* bhh    = (const float*)d_in[10];
    const float* W1     = (const float*)d_in[11];
    const float* b1v    = (const float*)d_in[12];
    const float* W2     = (const float*)d_in[13];
    const float* b2v    = (const float*)d_in[14];
    const float* lnx_g  = (const float*)d_in[15];
    const float* lnx_b  = (const float*)d_in[16];
    const float* lns_g  = (const float*)d_in[17];
    const float* lns_b  = (const float*)d_in[18];
    const float* lnff_g = (const float*)d_in[19];
    const float* lnff_b = (const float*)d_in[20];
    float* out = (float*)d_out;

    if (ws_size >= WS_REQ) {
        float* ws      = (float*)d_ws;
        float* slots   = ws;                                   // 16384
        float* qt      = ws + 16384;                           // 16384
        float* part_pa = ws + 32768;                           // Bn*Cn*Sn*Dn
        float* part_ps = part_pa + Bn * Cn * Sn * Dn;          // Bn*Cn*Sn
        unsigned short* ybuf = (unsigned short*)(part_ps + Bn * Cn * Sn);

        init_kernel<<<Bn, 128, 0, stream>>>(noise, mu, logsig, lns_g, lns_b, Wq, Wk,
                                            slots, qt);
        pass0_kernel<<<dim3(Cn, Bn), PT, 0, stream>>>(x, ybuf, qt, lnx_g, lnx_b,
                                                      part_pa, part_ps);
        update_kernel<<<Bn, 128, 0, stream>>>(part_pa, part_ps, Wv, Wih, Whh, bih, bhh,
                                              W1, b1v, W2, b2v, lns_g, lns_b,
                                              lnff_g, lnff_b, Wq, Wk, slots, qt, out, 0, 1);
        pass12_kernel<<<dim3(Cn, Bn), PT, 0, stream>>>(ybuf, qt, part_pa, part_ps);
        update_kernel<<<Bn, 128, 0, stream>>>(part_pa, part_ps, Wv, Wih, Whh, bih, bhh,
                                              W1, b1v, W2, b2v, lns_g, lns_b,
                                              lnff_g, lnff_b, Wq, Wk, slots, qt, out, 0, 1);
        pass12_kernel<<<dim3(Cn, Bn), PT, 0, stream>>>(ybuf, qt, part_pa, part_ps);
        update_kernel<<<Bn, 128, 0, stream>>>(part_pa, part_ps, Wv, Wih, Whh, bih, bhh,
                                              W1, b1v, W2, b2v, lns_g, lns_b,
                                              lnff_g, lnff_b, Wq, Wk, slots, qt, out, 1, 0);
    } else {
        slot_fused<<<Bn, TPB, 0, stream>>>(x, noise, mu, logsig, Wq, Wk, Wv,
                                           Wih, Whh, bih, bhh, W1, b1v, W2, b2v,
                                           lnx_g, lnx_b, lns_g, lns_b, lnff_g, lnff_b,
                                           out);
    }
}